// Round 1
// baseline (136.620 us; speedup 1.0000x reference)
//
#include <hip/hip_runtime.h>

// ---- types ----
typedef __bf16 bf8_t  __attribute__((ext_vector_type(8)));   // 8 x bf16 = 4 VGPR (MFMA A/B frag)
typedef float  f4_t   __attribute__((ext_vector_type(4)));   // MFMA C/D frag
typedef unsigned short us4_t __attribute__((ext_vector_type(4)));

#define N_ROWS 4096
#define D_K    1024
#define TEMP_INV 20.0f   // 1 / 0.05

// fp32 -> bf16, round-to-nearest-even (no NaN in this problem)
__device__ __forceinline__ unsigned short f2bf(float f) {
    unsigned int u = __builtin_bit_cast(unsigned int, f);
    u += 0x7fffu + ((u >> 16) & 1u);
    return (unsigned short)(u >> 16);
}

// async global->LDS, 16B per lane. LDS dest must be wave-uniform base + lane*16.
__device__ __forceinline__ void gl_lds16(const __bf16* g, __bf16* l) {
    __builtin_amdgcn_global_load_lds(
        (const __attribute__((address_space(1))) unsigned int*)g,
        (__attribute__((address_space(3))) unsigned int*)l,
        16, 0, 0);
}

// ---------------- row normalize: x / max(||x||, eps), fp32 -> bf16 ----------------
// one block (256 threads) per row of 1024 floats; each thread owns 4 elements
__global__ __launch_bounds__(256) void norm_rows_kernel(
    const float* __restrict__ in, unsigned short* __restrict__ out)
{
    const int row = blockIdx.x;
    const int t   = threadIdx.x;
    const float4* ip = (const float4*)(in + (size_t)row * D_K);
    float4 v = ip[t];
    float ss = v.x*v.x + v.y*v.y + v.z*v.z + v.w*v.w;
    #pragma unroll
    for (int off = 32; off > 0; off >>= 1)
        ss += __shfl_down(ss, off, 64);
    __shared__ float red[4];
    if ((t & 63) == 0) red[t >> 6] = ss;
    __syncthreads();
    float tot   = red[0] + red[1] + red[2] + red[3];
    float scale = 1.0f / fmaxf(sqrtf(tot), 1e-8f);
    us4_t o;
    o.x = f2bf(v.x * scale);
    o.y = f2bf(v.y * scale);
    o.z = f2bf(v.z * scale);
    o.w = f2bf(v.w * scale);
    *(us4_t*)(out + (size_t)row * D_K + t * 4) = o;
}

// ---------------- C = (A . B^T) * 20, A,B bf16 [4096][1024], C fp32 [4096][4096] ----------------
// m97 structure: 128x128 tile, BK=32, 4 waves (2x2), each wave 4x4 grid of 16x16x32 MFMA
__global__ __launch_bounds__(256) void cosim_gemm_kernel(
    const unsigned short* __restrict__ Aus,
    const unsigned short* __restrict__ Bus,
    float* __restrict__ C)
{
    const __bf16* A = (const __bf16*)Aus;
    const __bf16* B = (const __bf16*)Bus;

    // no padding: global_load_lds requires LDS dest contiguous in lane order
    __shared__ __align__(16) __bf16 As[128 * 32];
    __shared__ __align__(16) __bf16 Bs[128 * 32];

    const int t    = threadIdx.x;
    const int lane = t & 63;
    const int wid  = t >> 6;
    const int wm   = wid >> 1;   // 0..1  (M half)
    const int wn   = wid & 1;    // 0..1  (N half)
    const int bm   = blockIdx.x;
    const int bn   = blockIdx.y;

    // staging: thread t loads 16B from row (t/4), cols (t%4)*8 .. +8 of the tile
    // LDS offset = t*8 elems (= row-major [row][k] with stride 32, exactly lane-contiguous)
    const __bf16* ag = A + (size_t)(bm * 128 + (t >> 2)) * D_K + (t & 3) * 8;
    const __bf16* bg = B + (size_t)(bn * 128 + (t >> 2)) * D_K + (t & 3) * 8;
    __bf16* asd = As + t * 8;
    __bf16* bsd = Bs + t * 8;

    // fragment read base: A[m=lane&15][k=(lane>>4)*8 + j]
    const int l15  = lane & 15;
    const int quad = lane >> 4;
    const __bf16* ar = As + (wm * 64 + l15) * 32 + quad * 8;
    const __bf16* br = Bs + (wn * 64 + l15) * 32 + quad * 8;

    f4_t acc[4][4];
    #pragma unroll
    for (int mi = 0; mi < 4; mi++)
        #pragma unroll
        for (int ni = 0; ni < 4; ni++) {
            acc[mi][ni][0] = 0.f; acc[mi][ni][1] = 0.f;
            acc[mi][ni][2] = 0.f; acc[mi][ni][3] = 0.f;
        }

    for (int k0 = 0; k0 < D_K; k0 += 32) {
        gl_lds16(ag + k0,                      asd);
        gl_lds16(ag + (size_t)64 * D_K + k0,   asd + 2048);
        gl_lds16(bg + k0,                      bsd);
        gl_lds16(bg + (size_t)64 * D_K + k0,   bsd + 2048);
        __syncthreads();   // compiler emits s_waitcnt vmcnt(0) before s_barrier

        bf8_t af[4], bfr[4];
        #pragma unroll
        for (int mi = 0; mi < 4; mi++)
            af[mi] = *(const bf8_t*)(ar + mi * 16 * 32);
        #pragma unroll
        for (int ni = 0; ni < 4; ni++)
            bfr[ni] = *(const bf8_t*)(br + ni * 16 * 32);

        #pragma unroll
        for (int mi = 0; mi < 4; mi++)
            #pragma unroll
            for (int ni = 0; ni < 4; ni++)
                acc[mi][ni] = __builtin_amdgcn_mfma_f32_16x16x32_bf16(
                    af[mi], bfr[ni], acc[mi][ni], 0, 0, 0);

        __syncthreads();   // protect LDS before next stage overwrites
    }

    // epilogue: C/D layout col = lane&15, row = (lane>>4)*4 + reg  [m89/m91 verified]
    #pragma unroll
    for (int mi = 0; mi < 4; mi++) {
        #pragma unroll
        for (int ni = 0; ni < 4; ni++) {
            const int row = bm * 128 + wm * 64 + mi * 16 + quad * 4;
            const int col = bn * 128 + wn * 64 + ni * 16 + l15;
            #pragma unroll
            for (int r = 0; r < 4; r++)
                C[(size_t)(row + r) * N_ROWS + col] = acc[mi][ni][r] * TEMP_INV;
        }
    }
}

extern "C" void kernel_launch(void* const* d_in, const int* in_sizes, int n_in,
                              void* d_out, int out_size, void* d_ws, size_t ws_size,
                              hipStream_t stream)
{
    const float* x = (const float*)d_in[0];
    const float* y = (const float*)d_in[1];
    float* out = (float*)d_out;

    unsigned short* xb = (unsigned short*)d_ws;                 // 8 MB
    unsigned short* yb = xb + (size_t)N_ROWS * D_K;             // 8 MB

    norm_rows_kernel<<<N_ROWS, 256, 0, stream>>>(x, xb);
    norm_rows_kernel<<<N_ROWS, 256, 0, stream>>>(y, yb);

    dim3 grid(N_ROWS / 128, N_ROWS / 128);
    cosim_gemm_kernel<<<grid, 256, 0, stream>>>(xb, yb, out);
}

// Round 2
// 123.353 us; speedup vs baseline: 1.1076x; 1.1076x over previous
//
#include <hip/hip_runtime.h>

// ---- types ----
typedef __bf16 bf8_t  __attribute__((ext_vector_type(8)));   // 8 x bf16 = 4 VGPR (MFMA A/B frag)
typedef float  f4_t   __attribute__((ext_vector_type(4)));   // MFMA C/D frag
typedef unsigned short us4_t __attribute__((ext_vector_type(4)));

#define N_ROWS 4096
#define D_K    1024
#define TEMP_INV 20.0f   // 1 / 0.05

// fp32 -> bf16, round-to-nearest-even (no NaN in this problem)
__device__ __forceinline__ unsigned short f2bf(float f) {
    unsigned int u = __builtin_bit_cast(unsigned int, f);
    u += 0x7fffu + ((u >> 16) & 1u);
    return (unsigned short)(u >> 16);
}

// async global->LDS, 16B per lane. LDS dest must be wave-uniform base + lane*16.
__device__ __forceinline__ void gl_lds16(const __bf16* g, __bf16* l) {
    __builtin_amdgcn_global_load_lds(
        (const __attribute__((address_space(1))) unsigned int*)g,
        (__attribute__((address_space(3))) unsigned int*)l,
        16, 0, 0);
}

// ---------------- fused row normalize for both inputs: v / max(||v||, eps), fp32 -> bf16 ----
// blocks [0,4096) -> x, [4096,8192) -> y. One block (256 threads) per row of 1024 floats.
__global__ __launch_bounds__(256) void norm_rows_kernel(
    const float* __restrict__ x, const float* __restrict__ y,
    unsigned short* __restrict__ xb, unsigned short* __restrict__ yb)
{
    const int b   = blockIdx.x;
    const int row = b & (N_ROWS - 1);
    const float* in          = (b < N_ROWS) ? x  : y;
    unsigned short* out      = (b < N_ROWS) ? xb : yb;
    const int t = threadIdx.x;
    const float4* ip = (const float4*)(in + (size_t)row * D_K);
    float4 v = ip[t];
    float ss = v.x*v.x + v.y*v.y + v.z*v.z + v.w*v.w;
    #pragma unroll
    for (int off = 32; off > 0; off >>= 1)
        ss += __shfl_down(ss, off, 64);
    __shared__ float red[4];
    if ((t & 63) == 0) red[t >> 6] = ss;
    __syncthreads();
    float tot   = red[0] + red[1] + red[2] + red[3];
    float scale = 1.0f / fmaxf(sqrtf(tot), 1e-8f);
    us4_t o;
    o.x = f2bf(v.x * scale);
    o.y = f2bf(v.y * scale);
    o.z = f2bf(v.z * scale);
    o.w = f2bf(v.w * scale);
    *(us4_t*)(out + (size_t)row * D_K + t * 4) = o;
}

// ---------------- C = (A . B^T) * 20, A,B bf16 [4096][1024], C fp32 [4096][4096] ----------------
// 128x128 tile, BK=64, 4 waves (2x2), each wave 4x4 grid of 16x16x32 MFMA, 2 k-substeps/iter.
// LDS layout is XOR-swizzled: slot (row, g) holds global k-group g ^ (row & 7)  (g = 8-elem group).
// Swizzle is applied on the GLOBAL source address during staging (global_load_lds LDS dest is
// fixed to base + lane*16; permutation stays within each row's 128B segment so coalescing holds).
// Fragment ds_read_b128 start bank = 4*(g ^ (l15&7)) -> all 32 banks covered once per phase.
__global__ __launch_bounds__(256, 4) void cosim_gemm_kernel(
    const unsigned short* __restrict__ Aus,
    const unsigned short* __restrict__ Bus,
    float* __restrict__ C)
{
    const __bf16* A = (const __bf16*)Aus;
    const __bf16* B = (const __bf16*)Bus;

    __shared__ __align__(16) __bf16 As[128 * 64];   // 16 KB
    __shared__ __align__(16) __bf16 Bs[128 * 64];   // 16 KB

    const int t    = threadIdx.x;
    const int lane = t & 63;
    const int wid  = t >> 6;
    const int wm   = wid >> 1;   // 0..1  (M half)
    const int wn   = wid & 1;    // 0..1  (N half)
    const int bm   = blockIdx.x;
    const int bn   = blockIdx.y;

    // staging: thread t covers (row sr + 32*i, swizzled 8-elem group), 4 issues per matrix
    const int sr = t >> 3;                     // 0..31
    const int sg = (t & 7) ^ (sr & 7);         // swizzled source col-group
    const __bf16* ag = A + (size_t)(bm * 128 + sr) * D_K + sg * 8;
    const __bf16* bg = B + (size_t)(bn * 128 + sr) * D_K + sg * 8;
    __bf16* asd = As + t * 8;
    __bf16* bsd = Bs + t * 8;

    // fragment read bases: row rr needs global group (kk*4 + quad) at LDS slot (group ^ (rr&7))
    const int l15  = lane & 15;
    const int quad = lane >> 4;
    const int g0 = quad       ^ (l15 & 7);     // kk = 0
    const int g1 = (quad + 4) ^ (l15 & 7);     // kk = 1
    const __bf16* ar0 = As + (wm * 64 + l15) * 64 + g0 * 8;
    const __bf16* ar1 = As + (wm * 64 + l15) * 64 + g1 * 8;
    const __bf16* br0 = Bs + (wn * 64 + l15) * 64 + g0 * 8;
    const __bf16* br1 = Bs + (wn * 64 + l15) * 64 + g1 * 8;

    f4_t acc[4][4];
    #pragma unroll
    for (int mi = 0; mi < 4; mi++)
        #pragma unroll
        for (int ni = 0; ni < 4; ni++) {
            acc[mi][ni][0] = 0.f; acc[mi][ni][1] = 0.f;
            acc[mi][ni][2] = 0.f; acc[mi][ni][3] = 0.f;
        }

    for (int k0 = 0; k0 < D_K; k0 += 64) {
        #pragma unroll
        for (int i = 0; i < 4; i++) {
            gl_lds16(ag + (size_t)(32 * i) * D_K + k0, asd + 2048 * i);
            gl_lds16(bg + (size_t)(32 * i) * D_K + k0, bsd + 2048 * i);
        }
        __syncthreads();   // compiler emits s_waitcnt vmcnt(0) before s_barrier

        // kk = 0
        {
            bf8_t af[4], bfr[4];
            #pragma unroll
            for (int mi = 0; mi < 4; mi++) af[mi]  = *(const bf8_t*)(ar0 + mi * 16 * 64);
            #pragma unroll
            for (int ni = 0; ni < 4; ni++) bfr[ni] = *(const bf8_t*)(br0 + ni * 16 * 64);
            #pragma unroll
            for (int mi = 0; mi < 4; mi++)
                #pragma unroll
                for (int ni = 0; ni < 4; ni++)
                    acc[mi][ni] = __builtin_amdgcn_mfma_f32_16x16x32_bf16(
                        af[mi], bfr[ni], acc[mi][ni], 0, 0, 0);
        }
        // kk = 1
        {
            bf8_t af[4], bfr[4];
            #pragma unroll
            for (int mi = 0; mi < 4; mi++) af[mi]  = *(const bf8_t*)(ar1 + mi * 16 * 64);
            #pragma unroll
            for (int ni = 0; ni < 4; ni++) bfr[ni] = *(const bf8_t*)(br1 + ni * 16 * 64);
            #pragma unroll
            for (int mi = 0; mi < 4; mi++)
                #pragma unroll
                for (int ni = 0; ni < 4; ni++)
                    acc[mi][ni] = __builtin_amdgcn_mfma_f32_16x16x32_bf16(
                        af[mi], bfr[ni], acc[mi][ni], 0, 0, 0);
        }

        __syncthreads();   // protect LDS before next stage overwrites
    }

    // epilogue: C/D layout col = lane&15, row = (lane>>4)*4 + reg  [m89/m91 verified]
    #pragma unroll
    for (int mi = 0; mi < 4; mi++) {
        #pragma unroll
        for (int ni = 0; ni < 4; ni++) {
            const int row = bm * 128 + wm * 64 + mi * 16 + quad * 4;
            const int col = bn * 128 + wn * 64 + ni * 16 + l15;
            #pragma unroll
            for (int r = 0; r < 4; r++)
                C[(size_t)(row + r) * N_ROWS + col] = acc[mi][ni][r] * TEMP_INV;
        }
    }
}

extern "C" void kernel_launch(void* const* d_in, const int* in_sizes, int n_in,
                              void* d_out, int out_size, void* d_ws, size_t ws_size,
                              hipStream_t stream)
{
    const float* x = (const float*)d_in[0];
    const float* y = (const float*)d_in[1];
    float* out = (float*)d_out;

    unsigned short* xb = (unsigned short*)d_ws;                 // 8 MB
    unsigned short* yb = xb + (size_t)N_ROWS * D_K;             // 8 MB

    norm_rows_kernel<<<2 * N_ROWS, 256, 0, stream>>>(x, y, xb, yb);

    dim3 grid(N_ROWS / 128, N_ROWS / 128);
    cosim_gemm_kernel<<<grid, 256, 0, stream>>>(xb, yb, out);
}